// Round 7
// baseline (466.465 us; speedup 1.0000x reference)
//
#include <hip/hip_runtime.h>

#define D 128
#define NB_MAX 1024    // max final buckets (128 rows each; n_nodes/128 = 782)
#define NSB_STRIDE 64  // chunk_sb row stride (nsb <= 64)
#define CHN 4096       // edges per chunk
#define CAP 2560       // LDS edge capacity per bucket (mean 2046, +11 sigma)
#define SP 136         // padded LDS row stride (bf16 elems) for y tile

typedef short short8 __attribute__((ext_vector_type(8)));
typedef float floatx4 __attribute__((ext_vector_type(4)));

__device__ inline unsigned short f2bf(float f) {
  unsigned u = __float_as_uint(f);
  u += 0x7fffu + ((u >> 16) & 1u);   // round-to-nearest-even
  return (unsigned short)(u >> 16);
}

// ---------------------------------------------------------------------------
// K0: fused wf_pack (blocks 0..7) + per-chunk histogram (rest).
// chunk_hist[c][b] (b<nb) and chunk_sb[c][s] (s<nsb) are plain stores —
// no global atomics, no memset anywhere in the pipeline.
// ---------------------------------------------------------------------------
__global__ __launch_bounds__(256) void prep_kernel(
    const float* __restrict__ W, unsigned short* __restrict__ wf,
    const int* __restrict__ rows, int* __restrict__ chunk_hist,
    int* __restrict__ chunk_sb, int n_edges, int nb, int nsb) {
  __shared__ int h[NB_MAX];
  const int bid = blockIdx.x;
  const int t = threadIdx.x;

  if (bid < 8) {           // ---- wf_pack role ----
    int tid = bid * 256 + t;            // 0..2047
    int ks = tid >> 9;
    int rem = tid & 511;
    int nt = rem >> 6;
    int lane = rem & 63;
    int n = nt * 16 + (lane & 15);
    int k0 = ks * 32 + (lane >> 4) * 8;
    unsigned short v[8];
#pragma unroll
    for (int j = 0; j < 8; ++j) v[j] = f2bf(W[(k0 + j) * D + n]);
    uint4 o;
    o.x = (unsigned)v[0] | ((unsigned)v[1] << 16);
    o.y = (unsigned)v[2] | ((unsigned)v[3] << 16);
    o.z = (unsigned)v[4] | ((unsigned)v[5] << 16);
    o.w = (unsigned)v[6] | ((unsigned)v[7] << 16);
    ((uint4*)wf)[tid] = o;
    return;
  }

  // ---- histogram role ----
  int c = bid - 8;
  for (int i = t; i < NB_MAX; i += 256) h[i] = 0;
  __syncthreads();
  int lo = c * CHN;
  int hi = min(lo + CHN, n_edges);
  for (int i = lo + t; i < hi; i += 256) atomicAdd(&h[rows[i] >> 7], 1);
  __syncthreads();
  for (int b = t; b < nb; b += 256) chunk_hist[c * nb + b] = h[b];
  if (t < nsb) {
    int s = 0;
#pragma unroll
    for (int k = 0; k < 16; ++k) s += h[t * 16 + k];
    chunk_sb[c * NSB_STRIDE + t] = s;
  }
}

// ---------------------------------------------------------------------------
// K1 (P1): partition edges into nsb super-bucket regions (sb = row>>11).
// Block c < nchunks: derives its deterministic cell bases from chunk_sb
// (tot per sb + prefix over chunks < c), scatters its CHN edges with only
// LDS cursor atomics. Runs per (chunk,sb) ~ 84 edges = 672 B -> clean.
// Block c == nchunks: publishes bucket_off from chunk_hist column sums.
// Payload: ((row&2047)<<17)|col , val.
// ---------------------------------------------------------------------------
__global__ __launch_bounds__(1024) void p1_kernel(
    const int* __restrict__ rows, const int* __restrict__ cols,
    const float* __restrict__ vals, const int* __restrict__ chunk_hist,
    const int* __restrict__ chunk_sb, int* __restrict__ bucket_off,
    int2* __restrict__ tmp1, int n_edges, int nchunks, int nb, int nsb) {
  const int c = blockIdx.x;
  const int t = threadIdx.x;

  if (c == nchunks) {      // ---- scan role: publish bucket_off ----
    __shared__ int pscn[1024];
    int tot = 0;
    if (t < nb)
      for (int cc = 0; cc < nchunks; ++cc) tot += chunk_hist[cc * nb + t];
    pscn[t] = (t < nb) ? tot : 0;
    __syncthreads();
    for (int d = 1; d < 1024; d <<= 1) {
      int v = (t >= d) ? pscn[t - d] : 0;
      __syncthreads();
      pscn[t] += v;
      __syncthreads();
    }
    if (t < nb) bucket_off[t] = (t == 0) ? 0 : pscn[t - 1];
    if (t == 0) bucket_off[nb] = pscn[nb - 1];   // total = n_edges
    return;
  }

  __shared__ int sbt[NSB_STRIDE];      // sb totals
  __shared__ int sbo[NSB_STRIDE];      // sb exclusive offsets
  __shared__ int base_s[NSB_STRIDE];   // this chunk's cell base per sb
  __shared__ int h[NSB_STRIDE];        // local cursor
  if (t < nsb) {
    int tot = 0, pre = 0;
    for (int cc = 0; cc < nchunks; ++cc) {
      int v = chunk_sb[cc * NSB_STRIDE + t];
      tot += v;
      pre += (cc < c) ? v : 0;
    }
    sbt[t] = tot;
    base_s[t] = pre;
    h[t] = 0;
  }
  __syncthreads();
  if (t == 0) {
    int run = 0;
    for (int s = 0; s < nsb; ++s) { sbo[s] = run; run += sbt[s]; }
  }
  __syncthreads();
  if (t < nsb) base_s[t] += sbo[t];
  __syncthreads();

  int lo = c * CHN;
  int hi = min(lo + CHN, n_edges);
  for (int i = lo + t; i < hi; i += 1024) {
    int r = rows[i];
    int s = r >> 11;
    int l = atomicAdd(&h[s], 1);
    tmp1[base_s[s] + l] =
        make_int2(((r & 2047) << 17) | cols[i], __float_as_int(vals[i]));
  }
}

// ---------------------------------------------------------------------------
// K2 (P2): split each super-bucket into its 16 final buckets. 16 blocks per
// sb; slice j covers CHUNKS [c0,c1) so both its tmp1 read range and its
// per-bucket write bases are exact chunk_hist prefix sums — no cursors, no
// atomics. Runs per (slice,bucket) ~ 131 edges = 1 KB -> clean.
// bucket-in-sb = payload bits 24..27; final payload masks to 7 row bits.
// ---------------------------------------------------------------------------
__global__ __launch_bounds__(1024) void p2_kernel(
    const int* __restrict__ chunk_hist, const int* __restrict__ chunk_sb,
    const int* __restrict__ bucket_off, const int2* __restrict__ tmp1,
    int2* __restrict__ tmp2, int nchunks, int nb, int nsb) {
  __shared__ int wbase[16];   // global write base per bucket-in-sb
  __shared__ int h[16];       // local cursor
  __shared__ int cnt16[16];   // slice edge count per bucket
  __shared__ int ab[2];       // [a, bend)
  const int s = blockIdx.x >> 4;
  const int j = blockIdx.x & 15;
  const int t = threadIdx.x;
  const int c0 = (nchunks * j) >> 4;
  const int c1 = (nchunks * (j + 1)) >> 4;

  if (t < 16) {
    int b = (s << 4) + t;
    int pre = 0, cnt = 0;
    if (b < nb) {
      for (int cc = 0; cc < c1; ++cc) {
        int v = chunk_hist[cc * nb + b];
        pre += (cc < c0) ? v : 0;
        cnt += (cc >= c0) ? v : 0;
      }
      wbase[t] = bucket_off[b] + pre;
    } else {
      wbase[t] = 0;
    }
    cnt16[t] = cnt;
    h[t] = 0;
  }
  __syncthreads();
  if (t == 0) {
    // a = sb region start + sum of per-bucket prefixes within [0,c0)
    int sbstart = bucket_off[s << 4];
    int pre_sum = 0, cnt_sum = 0;
    for (int k = 0; k < 16; ++k) {
      int b = (s << 4) + k;
      if (b < nb) pre_sum += wbase[k] - bucket_off[b];
      cnt_sum += cnt16[k];
    }
    ab[0] = sbstart + pre_sum;
    ab[1] = sbstart + pre_sum + cnt_sum;
  }
  __syncthreads();
  const int a = ab[0], bend = ab[1];

  for (int i = a + t; i < bend; i += 1024) {
    int2 p = tmp1[i];
    int bi = (((unsigned)p.x) >> 24) & 15;
    int l = atomicAdd(&h[bi], 1);
    tmp2[wbase[bi] + l] = make_int2(p.x & 0x00FFFFFF, p.y);
  }
}

// ---------------------------------------------------------------------------
// K3: x -> bf16 cast, fully lane-contiguous (float4 in, uint2 out).
// Runs AFTER P2 (xh overlays tmp1's region).
// ---------------------------------------------------------------------------
__global__ __launch_bounds__(1024) void xcast_kernel(
    const float* __restrict__ x, unsigned int* __restrict__ xh2, int total4) {
  const float4* x4 = (const float4*)x;
  int base = blockIdx.x * 4096;
#pragma unroll
  for (int k = 0; k < 4; ++k) {
    int i = base + k * 1024 + threadIdx.x;
    if (i < total4) {
      float4 v = x4[i];
      unsigned lo = (unsigned)f2bf(v.x) | ((unsigned)f2bf(v.y) << 16);
      unsigned hi = (unsigned)f2bf(v.z) | ((unsigned)f2bf(v.w) << 16);
      ((uint2*)xh2)[i] = make_uint2(lo, hi);
    }
  }
}

// ---------------------------------------------------------------------------
// K4: fused in-LDS sort + register gather of y=adj@x + in-block MFMA GEMM.
// out = (adj@x)@W + rowsum⊗b.  One 1024-thr block (16 waves) per 128-row
// bucket. LDS phase overlay (69.6 KB -> 2 blocks/CU). Edge loop widened to
// 8 outstanding 256-B gathers per lane-slot (round-7 change).
// ---------------------------------------------------------------------------
__global__ __launch_bounds__(1024, 8) void gather_gemm_kernel(
    const uint2* __restrict__ xh, const unsigned short* __restrict__ wf,
    const float* __restrict__ bias, const int* __restrict__ bucket_off,
    const int2* __restrict__ tmp, float* __restrict__ out, int n_nodes) {
  __shared__ __align__(16) char U[67584];
  __shared__ int cnt[128];
  __shared__ int scn[128];
  __shared__ int rs[129];
  __shared__ float rowsum[128];
  unsigned short* ys = (unsigned short*)U;             // [0,34816)
  int2* ebuf = (int2*)U;                               // [0,20480)
  int2* sbuf = (int2*)(U + 34816);                     // [34816,55296)
  unsigned short* wfs = (unsigned short*)(U + 34816);  // [34816,67584)
  const int t = threadIdx.x;
  const int b = blockIdx.x;

  // prefetch W fragments to registers (T14: issue early, write late)
  const uint4* wf4 = (const uint4*)wf;
  uint4 wfr0 = wf4[t];
  uint4 wfr1 = wf4[t + 1024];

  const int lo = bucket_off[b];
  const int ne = bucket_off[b + 1] - lo;
  const int slot = t >> 5;       // 0..31
  const int lane = t & 31;

  if (ne <= CAP) {
    if (t < 128) cnt[t] = 0;
    __syncthreads();
    for (int i = t; i < ne; i += 1024) {
      int2 p = tmp[lo + i];
      ebuf[i] = p;
      atomicAdd(&cnt[((unsigned)p.x) >> 17], 1);
    }
    __syncthreads();
    if (t < 128) scn[t] = cnt[t];
    __syncthreads();
#pragma unroll
    for (int d = 1; d < 128; d <<= 1) {
      int v = (t < 128 && t >= d) ? scn[t - d] : 0;
      __syncthreads();
      if (t < 128) scn[t] += v;
      __syncthreads();
    }
    if (t < 128) {
      rs[t] = (t == 0) ? 0 : scn[t - 1];
      cnt[t] = 0;                // reuse as per-row cursor
    }
    __syncthreads();
    if (t == 0) rs[128] = scn[127];   // read only after next barrier
    for (int i = t; i < ne; i += 1024) {
      int2 p = ebuf[i];
      int r = ((unsigned)p.x) >> 17;
      int l = atomicAdd(&cnt[r], 1);
      sbuf[rs[r] + l] = p;
    }
    __syncthreads();
    // gather: slot handles rows slot, slot+32, ... ; y + rowsum per row
#pragma unroll
    for (int rr = 0; rr < 4; ++rr) {
      int row = slot + (rr << 5);
      int s = rs[row], e = rs[row + 1];
      float4 acc = make_float4(0.f, 0.f, 0.f, 0.f);
      float rsum = 0.f;
      int i = s;
      for (; i + 8 <= e; i += 8) {
        int2 p0 = sbuf[i + 0];
        int2 p1 = sbuf[i + 1];
        int2 p2 = sbuf[i + 2];
        int2 p3 = sbuf[i + 3];
        int2 p4 = sbuf[i + 4];
        int2 p5 = sbuf[i + 5];
        int2 p6 = sbuf[i + 6];
        int2 p7 = sbuf[i + 7];
        uint2 s0 = xh[((size_t)(p0.x & 0x1FFFF) << 5) + lane];
        uint2 s1 = xh[((size_t)(p1.x & 0x1FFFF) << 5) + lane];
        uint2 s2 = xh[((size_t)(p2.x & 0x1FFFF) << 5) + lane];
        uint2 s3 = xh[((size_t)(p3.x & 0x1FFFF) << 5) + lane];
        uint2 s4 = xh[((size_t)(p4.x & 0x1FFFF) << 5) + lane];
        uint2 s5 = xh[((size_t)(p5.x & 0x1FFFF) << 5) + lane];
        uint2 s6 = xh[((size_t)(p6.x & 0x1FFFF) << 5) + lane];
        uint2 s7 = xh[((size_t)(p7.x & 0x1FFFF) << 5) + lane];
        float v0 = __int_as_float(p0.y), v1 = __int_as_float(p1.y);
        float v2 = __int_as_float(p2.y), v3 = __int_as_float(p3.y);
        float v4 = __int_as_float(p4.y), v5 = __int_as_float(p5.y);
        float v6 = __int_as_float(p6.y), v7 = __int_as_float(p7.y);
        rsum += v0 + v1 + v2 + v3 + v4 + v5 + v6 + v7;
        acc.x += v0 * __uint_as_float(s0.x << 16);
        acc.y += v0 * __uint_as_float(s0.x & 0xffff0000u);
        acc.z += v0 * __uint_as_float(s0.y << 16);
        acc.w += v0 * __uint_as_float(s0.y & 0xffff0000u);
        acc.x += v1 * __uint_as_float(s1.x << 16);
        acc.y += v1 * __uint_as_float(s1.x & 0xffff0000u);
        acc.z += v1 * __uint_as_float(s1.y << 16);
        acc.w += v1 * __uint_as_float(s1.y & 0xffff0000u);
        acc.x += v2 * __uint_as_float(s2.x << 16);
        acc.y += v2 * __uint_as_float(s2.x & 0xffff0000u);
        acc.z += v2 * __uint_as_float(s2.y << 16);
        acc.w += v2 * __uint_as_float(s2.y & 0xffff0000u);
        acc.x += v3 * __uint_as_float(s3.x << 16);
        acc.y += v3 * __uint_as_float(s3.x & 0xffff0000u);
        acc.z += v3 * __uint_as_float(s3.y << 16);
        acc.w += v3 * __uint_as_float(s3.y & 0xffff0000u);
        acc.x += v4 * __uint_as_float(s4.x << 16);
        acc.y += v4 * __uint_as_float(s4.x & 0xffff0000u);
        acc.z += v4 * __uint_as_float(s4.y << 16);
        acc.w += v4 * __uint_as_float(s4.y & 0xffff0000u);
        acc.x += v5 * __uint_as_float(s5.x << 16);
        acc.y += v5 * __uint_as_float(s5.x & 0xffff0000u);
        acc.z += v5 * __uint_as_float(s5.y << 16);
        acc.w += v5 * __uint_as_float(s5.y & 0xffff0000u);
        acc.x += v6 * __uint_as_float(s6.x << 16);
        acc.y += v6 * __uint_as_float(s6.x & 0xffff0000u);
        acc.z += v6 * __uint_as_float(s6.y << 16);
        acc.w += v6 * __uint_as_float(s6.y & 0xffff0000u);
        acc.x += v7 * __uint_as_float(s7.x << 16);
        acc.y += v7 * __uint_as_float(s7.x & 0xffff0000u);
        acc.z += v7 * __uint_as_float(s7.y << 16);
        acc.w += v7 * __uint_as_float(s7.y & 0xffff0000u);
      }
      for (; i < e; ++i) {
        int2 p = sbuf[i];
        float v = __int_as_float(p.y);
        uint2 sv = xh[((size_t)(p.x & 0x1FFFF) << 5) + lane];
        rsum += v;
        acc.x += v * __uint_as_float(sv.x << 16);
        acc.y += v * __uint_as_float(sv.x & 0xffff0000u);
        acc.z += v * __uint_as_float(sv.y << 16);
        acc.w += v * __uint_as_float(sv.y & 0xffff0000u);
      }
      unsigned u0 = (unsigned)f2bf(acc.x) | ((unsigned)f2bf(acc.y) << 16);
      unsigned u1 = (unsigned)f2bf(acc.z) | ((unsigned)f2bf(acc.w) << 16);
      *((uint2*)(ys + row * SP + lane * 4)) = make_uint2(u0, u1);
      if (lane == 0) rowsum[row] = rsum;
    }
  } else {
    // fallback (ne > CAP, ~ +11 sigma): filtered global scan (exact)
#pragma unroll
    for (int rr = 0; rr < 4; ++rr) {
      int row = slot + (rr << 5);
      float4 acc = make_float4(0.f, 0.f, 0.f, 0.f);
      float rsum = 0.f;
      for (int i = 0; i < ne; ++i) {
        int2 p = tmp[lo + i];
        if ((int)(((unsigned)p.x) >> 17) != row) continue;
        float v = __int_as_float(p.y);
        uint2 sv = xh[((size_t)(p.x & 0x1FFFF) << 5) + lane];
        rsum += v;
        acc.x += v * __uint_as_float(sv.x << 16);
        acc.y += v * __uint_as_float(sv.x & 0xffff0000u);
        acc.z += v * __uint_as_float(sv.y << 16);
        acc.w += v * __uint_as_float(sv.y & 0xffff0000u);
      }
      unsigned u0 = (unsigned)f2bf(acc.x) | ((unsigned)f2bf(acc.y) << 16);
      unsigned u1 = (unsigned)f2bf(acc.z) | ((unsigned)f2bf(acc.w) << 16);
      *((uint2*)(ys + row * SP + lane * 4)) = make_uint2(u0, u1);
      if (lane == 0) rowsum[row] = rsum;
    }
  }
  __syncthreads();

  // drop prefetched W fragments into LDS (over dead sbuf)
  uint4* wfs4 = (uint4*)wfs;
  wfs4[t] = wfr0;
  wfs4[t + 1024] = wfr1;
  __syncthreads();

  // in-block GEMM: 16 waves, each 32x32 of the 128x128 tile
  const int l64 = t & 63;
  const int w = t >> 6;
  const int m = l64 & 15, q = l64 >> 4;
  const int rb = (w & 3) * 32;
  const int cb = (w >> 2) * 32;

  floatx4 acc2[2][2];
#pragma unroll
  for (int rt = 0; rt < 2; ++rt)
#pragma unroll
    for (int ct = 0; ct < 2; ++ct) {
      acc2[rt][ct][0] = 0.f; acc2[rt][ct][1] = 0.f;
      acc2[rt][ct][2] = 0.f; acc2[rt][ct][3] = 0.f;
    }

#pragma unroll
  for (int ks = 0; ks < 4; ++ks) {
    short8 af[2], bfr[2];
#pragma unroll
    for (int rt = 0; rt < 2; ++rt)
      af[rt] = *((const short8*)(ys + (rb + rt * 16 + m) * SP + ks * 32 + q * 8));
#pragma unroll
    for (int ct = 0; ct < 2; ++ct) {
      int nt = (cb >> 4) + ct;
      bfr[ct] = *((const short8*)(wfs + ((ks * 8 + nt) * 64 + l64) * 8));
    }
#pragma unroll
    for (int rt = 0; rt < 2; ++rt)
#pragma unroll
      for (int ct = 0; ct < 2; ++ct)
        acc2[rt][ct] = __builtin_amdgcn_mfma_f32_16x16x32_bf16(
            af[rt], bfr[ct], acc2[rt][ct], 0, 0, 0);
  }

  // epilogue: out = acc + rowsum[row]*b[col]; C/D map row=(lane>>4)*4+r, col=m
  float b0 = bias[cb + m];
  float b1 = bias[cb + 16 + m];
#pragma unroll
  for (int rt = 0; rt < 2; ++rt)
#pragma unroll
    for (int ct = 0; ct < 2; ++ct) {
      float bc = ct ? b1 : b0;
#pragma unroll
      for (int r = 0; r < 4; ++r) {
        int row = rb + rt * 16 + q * 4 + r;
        int col = cb + ct * 16 + m;
        int node = (b << 7) + row;
        if (node < n_nodes)
          out[(size_t)node * D + col] = acc2[rt][ct][r] + rowsum[row] * bc;
      }
    }
}

extern "C" void kernel_launch(void* const* d_in, const int* in_sizes, int n_in,
                              void* d_out, int out_size, void* d_ws, size_t ws_size,
                              hipStream_t stream) {
  const float* x    = (const float*)d_in[0];
  const int*   rows = (const int*)d_in[1];
  const int*   cols = (const int*)d_in[2];
  const float* vals = (const float*)d_in[3];
  const float* W    = (const float*)d_in[4];
  const float* b    = (const float*)d_in[5];
  float* out = (float*)d_out;

  int n_nodes = in_sizes[0] / D;
  int n_edges = in_sizes[1];
  int nb = (n_nodes + 127) >> 7;              // 782 final buckets
  int nsb = (nb + 15) >> 4;                   // 49 super-buckets
  int nchunks = (n_edges + CHN - 1) / CHN;    // 391 chunks
  int total_elems = n_nodes * D;

  // Workspace overlay (peak 38.44 MB, proven budget):
  //   [0, 12.8M)      tmp1 (SB-partitioned edges)  -- dead after P2
  //   [0, 25.6M)      xh (bf16 x)                  -- written by xcast after P2
  //   [25.6M, 38.4M)  tmp2 (bucket-partitioned edges, packed)
  //   [38.4M, ...)    bucket_off (nb+1 ints) + wf (32 KB)
  // chunk_hist (nchunks*nb ints ~1.23 MB) + chunk_sb (nchunks*64 ints) live
  // in `out` as scratch (written K0, read P1/P2, dead before K4 writes out).
  char* ws = (char*)d_ws;
  int2* tmp1         = (int2*)(ws);
  unsigned short* xh = (unsigned short*)(ws);
  int2* tmp2         = (int2*)(ws + 25600000);
  char* mb           = ws + 38400000;
  int* bucket_off    = (int*)(mb);                      //  4,096 B
  unsigned short* wf = (unsigned short*)(mb + 4096);    // 32,768 B
  int* chunk_hist    = (int*)out;
  int* chunk_sb      = (int*)((char*)out + 2000000);

  prep_kernel<<<dim3(8 + nchunks), dim3(256), 0, stream>>>(
      W, wf, rows, chunk_hist, chunk_sb, n_edges, nb, nsb);

  p1_kernel<<<dim3(nchunks + 1), dim3(1024), 0, stream>>>(
      rows, cols, vals, chunk_hist, chunk_sb, bucket_off, tmp1,
      n_edges, nchunks, nb, nsb);

  p2_kernel<<<dim3(nsb * 16), dim3(1024), 0, stream>>>(
      chunk_hist, chunk_sb, bucket_off, tmp1, tmp2, nchunks, nb, nsb);

  int total4 = total_elems >> 2;
  xcast_kernel<<<dim3((total4 + 4095) / 4096), dim3(1024), 0, stream>>>(
      x, (unsigned int*)xh, total4);

  gather_gemm_kernel<<<dim3(nb), dim3(1024), 0, stream>>>(
      (const uint2*)xh, wf, b, bucket_off, tmp2, out, n_nodes);
}

// Round 8
// 236.495 us; speedup vs baseline: 1.9724x; 1.9724x over previous
//
#include <hip/hip_runtime.h>

#define D 128
#define SBMAX 64      // max super-buckets (2048 rows each; 49 here)
#define CSTRIDE 400   // chunk_sb row stride in ints (>= nchunks)
#define CHN 4096      // edges per chunk
#define CAP 2560      // LDS edge capacity per 128-row bucket (+11 sigma)
#define SP 136        // padded LDS row stride (bf16 elems) for y tile

typedef short short8 __attribute__((ext_vector_type(8)));
typedef float floatx4 __attribute__((ext_vector_type(4)));

__device__ inline unsigned short f2bf(float f) {
  unsigned u = __float_as_uint(f);
  u += 0x7fffu + ((u >> 16) & 1u);   // round-to-nearest-even
  return (unsigned short)(u >> 16);
}

// ---------------------------------------------------------------------------
// K0: fused independent roles (one dispatch, no cross-role deps):
//   blocks [0,2)                 : wf pack (W -> MFMA B-fragment bf16)
//   blocks [2, 2+nchunks)        : per-chunk super-bucket histogram (49 bins)
//                                  -> chunk_sb[s][c] TRANSPOSED plain stores
//   blocks [2+nchunks, ...)      : x -> bf16 cast (xh, lane-contiguous)
// No global atomics, no memset.
// ---------------------------------------------------------------------------
__global__ __launch_bounds__(1024) void prep_kernel(
    const float* __restrict__ W, unsigned short* __restrict__ wf,
    const float* __restrict__ x, unsigned int* __restrict__ xh2,
    const int* __restrict__ rows, int* __restrict__ chunk_sb,
    int n_edges, int nchunks, int nsb, int total4) {
  __shared__ int h[SBMAX];
  const int bid = blockIdx.x;
  const int t = threadIdx.x;

  if (bid < 2) {              // ---- wf_pack role (2048 entries) ----
    int tid = bid * 1024 + t;
    int ks = tid >> 9;
    int rem = tid & 511;
    int nt = rem >> 6;
    int lane = rem & 63;
    int n = nt * 16 + (lane & 15);
    int k0 = ks * 32 + (lane >> 4) * 8;
    unsigned short v[8];
#pragma unroll
    for (int j = 0; j < 8; ++j) v[j] = f2bf(W[(k0 + j) * D + n]);
    uint4 o;
    o.x = (unsigned)v[0] | ((unsigned)v[1] << 16);
    o.y = (unsigned)v[2] | ((unsigned)v[3] << 16);
    o.z = (unsigned)v[4] | ((unsigned)v[5] << 16);
    o.w = (unsigned)v[6] | ((unsigned)v[7] << 16);
    ((uint4*)wf)[tid] = o;
    return;
  }

  if (bid < 2 + nchunks) {    // ---- histogram role ----
    if (t < SBMAX) h[t] = 0;
    __syncthreads();
    int c = bid - 2;
    int lo = c * CHN;
    int hi = min(lo + CHN, n_edges);
    for (int i = lo + t; i < hi; i += 1024) atomicAdd(&h[rows[i] >> 11], 1);
    __syncthreads();
    if (t < nsb) chunk_sb[t * CSTRIDE + c] = h[t];   // transposed store
    return;
  }

  // ---- xcast role: 4 float4 -> 4 uint2 per thread ----
  const float4* x4 = (const float4*)x;
  int base = (bid - 2 - nchunks) * 4096;
#pragma unroll
  for (int k = 0; k < 4; ++k) {
    int i = base + k * 1024 + t;
    if (i < total4) {
      float4 v = x4[i];
      unsigned lo = (unsigned)f2bf(v.x) | ((unsigned)f2bf(v.y) << 16);
      unsigned hi = (unsigned)f2bf(v.z) | ((unsigned)f2bf(v.w) << 16);
      ((uint2*)xh2)[i] = make_uint2(lo, hi);
    }
  }
}

// ---------------------------------------------------------------------------
// K1 (P1): partition edges into nsb super-bucket regions (sb = row>>11).
// Setup is block-parallel + contiguous (round-7 fix): 16 threads per sb each
// sum a 25-chunk strip of the TRANSPOSED chunk_sb row -> totals and this
// chunk's prefix; LDS-reduce; t==0 scans 49 sb totals. Block 0 publishes
// sb_off. Scatter runs ~84 edges = 672 B per (chunk,sb) -> clean lines.
// Payload: ((row&2047)<<17)|col , val.
// ---------------------------------------------------------------------------
__global__ __launch_bounds__(1024) void p1_kernel(
    const int* __restrict__ rows, const int* __restrict__ cols,
    const float* __restrict__ vals, const int* __restrict__ chunk_sb,
    int* __restrict__ sb_off, int2* __restrict__ tmp1,
    int n_edges, int nchunks, int nsb) {
  __shared__ int ptot[1024];
  __shared__ int ppre[1024];
  __shared__ int sbt[SBMAX];
  __shared__ int sbo[SBMAX + 1];
  __shared__ int base_s[SBMAX];
  __shared__ int h[SBMAX];
  const int c = blockIdx.x;
  const int t = threadIdx.x;

  {
    int s = t >> 4, g = t & 15;
    int tp = 0, pp = 0;
    if (s < nsb) {
      int strip = (nchunks + 15) >> 4;          // 25
      int a = g * strip;
      int b2 = min(a + strip, nchunks);
      const int* rowp = chunk_sb + s * CSTRIDE;
      for (int cc = a; cc < b2; ++cc) {
        int v = rowp[cc];
        tp += v;
        pp += (cc < c) ? v : 0;
      }
    }
    ptot[t] = tp;
    ppre[t] = pp;
  }
  __syncthreads();
  if (t < nsb) {
    int tp = 0, pp = 0;
#pragma unroll
    for (int g = 0; g < 16; ++g) { tp += ptot[(t << 4) + g]; pp += ppre[(t << 4) + g]; }
    sbt[t] = tp;
    base_s[t] = pp;
    h[t] = 0;
  }
  __syncthreads();
  if (t == 0) {
    int run = 0;
    for (int s = 0; s < nsb; ++s) { sbo[s] = run; run += sbt[s]; }
    sbo[nsb] = run;   // == n_edges
  }
  __syncthreads();
  if (t < nsb) base_s[t] += sbo[t];
  if (c == 0 && t <= nsb) sb_off[t] = sbo[t];
  __syncthreads();

  int lo = c * CHN;
  int hi = min(lo + CHN, n_edges);
  for (int i = lo + t; i < hi; i += 1024) {
    int r = rows[i];
    int s = r >> 11;
    int l = atomicAdd(&h[s], 1);
    tmp1[base_s[s] + l] =
        make_int2(((r & 2047) << 17) | cols[i], __float_as_int(vals[i]));
  }
}

// ---------------------------------------------------------------------------
// K2: filter + in-LDS sort + register gather of y=adj@x + in-block MFMA GEMM.
// 16 sibling blocks per super-bucket each filter their 128-row window out of
// the sb's ~33K-edge region (coalesced pass). bid swizzle pins all 16
// siblings of sb s to XCD (s%8) assuming round-robin bid->XCD: region is
// HBM-fetched once per sb, siblings hit L2. Then the proven sort + unroll-4
// register gather + 128x128x128 MFMA GEMM. out = (adj@x)@W + rowsum⊗b.
// LDS overlay 69.6 KB -> 2 blocks/CU.
// ---------------------------------------------------------------------------
__global__ __launch_bounds__(1024, 8) void gather_gemm_kernel(
    const uint2* __restrict__ xh, const unsigned short* __restrict__ wf,
    const float* __restrict__ bias, const int* __restrict__ sb_off,
    const int2* __restrict__ tmp1, float* __restrict__ out,
    int n_nodes, int nsb) {
  __shared__ __align__(16) char U[67584];
  __shared__ int cnt[128];
  __shared__ int scn[128];
  __shared__ int rs[129];
  __shared__ float rowsum[128];
  __shared__ int fc;
  unsigned short* ys = (unsigned short*)U;             // [0,34816)
  int2* ebuf = (int2*)U;                               // [0,20480)
  int2* sbuf = (int2*)(U + 34816);                     // [34816,55296)
  unsigned short* wfs = (unsigned short*)(U + 34816);  // [34816,67584)
  const int t = threadIdx.x;

  // de-swizzle: all 16 siblings of sb share bid%8 -> same XCD
  const int xcd = blockIdx.x & 7;
  const int mg = blockIdx.x >> 3;
  const int jj = mg & 15;            // 128-row window within sb
  const int sbi = (mg >> 4) * 8 + xcd;
  if (sbi >= nsb) return;
  const int node0 = ((sbi << 4) + jj) << 7;
  if (node0 >= n_nodes) return;

  // prefetch W fragments to registers (issue early, write late)
  const uint4* wf4 = (const uint4*)wf;
  uint4 wfr0 = wf4[t];
  uint4 wfr1 = wf4[t + 1024];

  const int lo = sb_off[sbi];
  const int rne = sb_off[sbi + 1] - lo;
  const int slot = t >> 5;       // 0..31
  const int lane = t & 31;

  // ---- filter phase: extract this block's 128 rows from the sb region ----
  if (t < 128) cnt[t] = 0;
  if (t == 0) fc = 0;
  __syncthreads();
  for (int i = t; i < rne; i += 1024) {
    int2 p = tmp1[lo + i];
    int lr = ((unsigned)p.x) >> 17;          // 11-bit local row in sb
    if ((lr >> 7) == jj) {
      int pos = atomicAdd(&fc, 1);
      if (pos < CAP) ebuf[pos] = p;
      atomicAdd(&cnt[lr & 127], 1);
    }
  }
  __syncthreads();
  const int ne = fc;

  if (ne <= CAP) {
    // 128-wide scan of cnt -> row starts
    if (t < 128) scn[t] = cnt[t];
    __syncthreads();
#pragma unroll
    for (int d = 1; d < 128; d <<= 1) {
      int v = (t < 128 && t >= d) ? scn[t - d] : 0;
      __syncthreads();
      if (t < 128) scn[t] += v;
      __syncthreads();
    }
    if (t < 128) {
      rs[t] = (t == 0) ? 0 : scn[t - 1];
      cnt[t] = 0;                // reuse as per-row cursor
    }
    __syncthreads();
    if (t == 0) rs[128] = scn[127];   // read only after next barrier
    for (int i = t; i < ne; i += 1024) {
      int2 p = ebuf[i];
      int r = (((unsigned)p.x) >> 17) & 127;
      int l = atomicAdd(&cnt[r], 1);
      sbuf[rs[r] + l] = p;
    }
    __syncthreads();
    // register gather: slot handles rows slot, slot+32, ...
#pragma unroll
    for (int rr = 0; rr < 4; ++rr) {
      int row = slot + (rr << 5);
      int s = rs[row], e = rs[row + 1];
      float4 acc = make_float4(0.f, 0.f, 0.f, 0.f);
      float rsum = 0.f;
      int i = s;
      for (; i + 4 <= e; i += 4) {
        int2 p0 = sbuf[i + 0];
        int2 p1 = sbuf[i + 1];
        int2 p2 = sbuf[i + 2];
        int2 p3 = sbuf[i + 3];
        uint2 s0 = xh[((size_t)(p0.x & 0x1FFFF) << 5) + lane];
        uint2 s1 = xh[((size_t)(p1.x & 0x1FFFF) << 5) + lane];
        uint2 s2 = xh[((size_t)(p2.x & 0x1FFFF) << 5) + lane];
        uint2 s3 = xh[((size_t)(p3.x & 0x1FFFF) << 5) + lane];
        float v0 = __int_as_float(p0.y), v1 = __int_as_float(p1.y);
        float v2 = __int_as_float(p2.y), v3 = __int_as_float(p3.y);
        rsum += v0 + v1 + v2 + v3;
        acc.x += v0 * __uint_as_float(s0.x << 16);
        acc.y += v0 * __uint_as_float(s0.x & 0xffff0000u);
        acc.z += v0 * __uint_as_float(s0.y << 16);
        acc.w += v0 * __uint_as_float(s0.y & 0xffff0000u);
        acc.x += v1 * __uint_as_float(s1.x << 16);
        acc.y += v1 * __uint_as_float(s1.x & 0xffff0000u);
        acc.z += v1 * __uint_as_float(s1.y << 16);
        acc.w += v1 * __uint_as_float(s1.y & 0xffff0000u);
        acc.x += v2 * __uint_as_float(s2.x << 16);
        acc.y += v2 * __uint_as_float(s2.x & 0xffff0000u);
        acc.z += v2 * __uint_as_float(s2.y << 16);
        acc.w += v2 * __uint_as_float(s2.y & 0xffff0000u);
        acc.x += v3 * __uint_as_float(s3.x << 16);
        acc.y += v3 * __uint_as_float(s3.x & 0xffff0000u);
        acc.z += v3 * __uint_as_float(s3.y << 16);
        acc.w += v3 * __uint_as_float(s3.y & 0xffff0000u);
      }
      for (; i < e; ++i) {
        int2 p = sbuf[i];
        float v = __int_as_float(p.y);
        uint2 sv = xh[((size_t)(p.x & 0x1FFFF) << 5) + lane];
        rsum += v;
        acc.x += v * __uint_as_float(sv.x << 16);
        acc.y += v * __uint_as_float(sv.x & 0xffff0000u);
        acc.z += v * __uint_as_float(sv.y << 16);
        acc.w += v * __uint_as_float(sv.y & 0xffff0000u);
      }
      unsigned u0 = (unsigned)f2bf(acc.x) | ((unsigned)f2bf(acc.y) << 16);
      unsigned u1 = (unsigned)f2bf(acc.z) | ((unsigned)f2bf(acc.w) << 16);
      *((uint2*)(ys + row * SP + lane * 4)) = make_uint2(u0, u1);
      if (lane == 0) rowsum[row] = rsum;
    }
  } else {
    // fallback (ne > CAP, ~ +11 sigma): filtered scan of the sb region
#pragma unroll
    for (int rr = 0; rr < 4; ++rr) {
      int row = slot + (rr << 5);
      int tgt = (jj << 7) | row;
      float4 acc = make_float4(0.f, 0.f, 0.f, 0.f);
      float rsum = 0.f;
      for (int i = 0; i < rne; ++i) {
        int2 p = tmp1[lo + i];
        if ((int)(((unsigned)p.x) >> 17) != tgt) continue;
        float v = __int_as_float(p.y);
        uint2 sv = xh[((size_t)(p.x & 0x1FFFF) << 5) + lane];
        rsum += v;
        acc.x += v * __uint_as_float(sv.x << 16);
        acc.y += v * __uint_as_float(sv.x & 0xffff0000u);
        acc.z += v * __uint_as_float(sv.y << 16);
        acc.w += v * __uint_as_float(sv.y & 0xffff0000u);
      }
      unsigned u0 = (unsigned)f2bf(acc.x) | ((unsigned)f2bf(acc.y) << 16);
      unsigned u1 = (unsigned)f2bf(acc.z) | ((unsigned)f2bf(acc.w) << 16);
      *((uint2*)(ys + row * SP + lane * 4)) = make_uint2(u0, u1);
      if (lane == 0) rowsum[row] = rsum;
    }
  }
  __syncthreads();

  // drop prefetched W fragments into LDS (over dead sbuf)
  uint4* wfs4 = (uint4*)wfs;
  wfs4[t] = wfr0;
  wfs4[t + 1024] = wfr1;
  __syncthreads();

  // in-block GEMM: 16 waves, each 32x32 of the 128x128 tile
  const int l64 = t & 63;
  const int w = t >> 6;
  const int m = l64 & 15, q = l64 >> 4;
  const int rb = (w & 3) * 32;
  const int cb = (w >> 2) * 32;

  floatx4 acc2[2][2];
#pragma unroll
  for (int rt = 0; rt < 2; ++rt)
#pragma unroll
    for (int ct = 0; ct < 2; ++ct) {
      acc2[rt][ct][0] = 0.f; acc2[rt][ct][1] = 0.f;
      acc2[rt][ct][2] = 0.f; acc2[rt][ct][3] = 0.f;
    }

#pragma unroll
  for (int ks = 0; ks < 4; ++ks) {
    short8 af[2], bfr[2];
#pragma unroll
    for (int rt = 0; rt < 2; ++rt)
      af[rt] = *((const short8*)(ys + (rb + rt * 16 + m) * SP + ks * 32 + q * 8));
#pragma unroll
    for (int ct = 0; ct < 2; ++ct) {
      int nt = (cb >> 4) + ct;
      bfr[ct] = *((const short8*)(wfs + ((ks * 8 + nt) * 64 + l64) * 8));
    }
#pragma unroll
    for (int rt = 0; rt < 2; ++rt)
#pragma unroll
      for (int ct = 0; ct < 2; ++ct)
        acc2[rt][ct] = __builtin_amdgcn_mfma_f32_16x16x32_bf16(
            af[rt], bfr[ct], acc2[rt][ct], 0, 0, 0);
  }

  // epilogue: out = acc + rowsum[row]*b[col]; C/D map row=(lane>>4)*4+r, col=m
  float b0 = bias[cb + m];
  float b1 = bias[cb + 16 + m];
#pragma unroll
  for (int rt = 0; rt < 2; ++rt)
#pragma unroll
    for (int ct = 0; ct < 2; ++ct) {
      float bc = ct ? b1 : b0;
#pragma unroll
      for (int r = 0; r < 4; ++r) {
        int row = rb + rt * 16 + q * 4 + r;
        int col = cb + ct * 16 + m;
        int node = node0 + row;
        if (node < n_nodes)
          out[(size_t)node * D + col] = acc2[rt][ct][r] + rowsum[row] * bc;
      }
    }
}

extern "C" void kernel_launch(void* const* d_in, const int* in_sizes, int n_in,
                              void* d_out, int out_size, void* d_ws, size_t ws_size,
                              hipStream_t stream) {
  const float* x    = (const float*)d_in[0];
  const int*   rows = (const int*)d_in[1];
  const int*   cols = (const int*)d_in[2];
  const float* vals = (const float*)d_in[3];
  const float* W    = (const float*)d_in[4];
  const float* b    = (const float*)d_in[5];
  float* out = (float*)d_out;

  int n_nodes = in_sizes[0] / D;
  int n_edges = in_sizes[1];
  int nb = (n_nodes + 127) >> 7;              // 782 final buckets
  int nsb = (nb + 15) >> 4;                   // 49 super-buckets
  int nchunks = (n_edges + CHN - 1) / CHN;    // 391 chunks
  int total_elems = n_nodes * D;
  int total4 = total_elems >> 2;

  // Workspace (38.44 MB, proven budget):
  //   [0, 25.6M)      xh (bf16 x)
  //   [25.6M, 38.4M)  tmp1 (SB-partitioned edges)
  //   [38.4M, ...)    sb_off (nsb+1 ints) + wf (32 KB)
  // chunk_sb (49 x CSTRIDE ints = 78 KB) lives in `out` as scratch
  // (written K0, read K1, dead before K2 writes out).
  char* ws = (char*)d_ws;
  unsigned short* xh = (unsigned short*)(ws);
  int2* tmp1         = (int2*)(ws + 25600000);
  char* mb           = ws + 38400000;
  int* sb_off        = (int*)(mb);                      //    512 B
  unsigned short* wf = (unsigned short*)(mb + 512);     // 32,768 B
  int* chunk_sb      = (int*)out;

  int cblocks = (total4 + 4095) / 4096;       // 782
  prep_kernel<<<dim3(2 + nchunks + cblocks), dim3(1024), 0, stream>>>(
      W, wf, x, (unsigned int*)xh, rows, chunk_sb,
      n_edges, nchunks, nsb, total4);

  p1_kernel<<<dim3(nchunks), dim3(1024), 0, stream>>>(
      rows, cols, vals, chunk_sb, sb_off, tmp1, n_edges, nchunks, nsb);

  int ggrid = ((nsb + 7) >> 3) * 8 * 16;      // 896 (swizzle-padded)
  gather_gemm_kernel<<<dim3(ggrid), dim3(1024), 0, stream>>>(
      (const uint2*)xh, wf, b, sb_off, tmp1, out, n_nodes, nsb);
}

// Round 9
// 232.081 us; speedup vs baseline: 2.0099x; 1.0190x over previous
//
#include <hip/hip_runtime.h>

#define D 128
#define NB_MAX 1024    // LDS hist bins (nb = 782 final buckets of 128 rows)
#define SBMAX 64       // max super-buckets (49 here, 2048 rows each)
#define CSTRIDE 512    // transposed table row stride in ints (>= nchunks)
#define CHN 4096       // edges per chunk
#define CAP 2560       // LDS edge capacity per bucket (mean 2046, +11 sigma)
#define SP 136         // padded LDS row stride (bf16 elems) for y tile

typedef short short8 __attribute__((ext_vector_type(8)));
typedef float floatx4 __attribute__((ext_vector_type(4)));

__device__ inline unsigned short f2bf(float f) {
  unsigned u = __float_as_uint(f);
  u += 0x7fffu + ((u >> 16) & 1u);   // round-to-nearest-even
  return (unsigned short)(u >> 16);
}

// ---------------------------------------------------------------------------
// K0: fused wf_pack (blocks 0..1) + per-chunk bucket histogram (rest).
// Writes TRANSPOSED tables (contiguous per-bucket rows, the R7 lesson):
//   chunk_hist[b*CSTRIDE + c]  (782 rows)   chunk_sb[s*CSTRIDE + c] (49 rows)
// Plain stores, no global atomics, no memset anywhere in the pipeline.
// ---------------------------------------------------------------------------
__global__ __launch_bounds__(1024) void prep_kernel(
    const float* __restrict__ W, unsigned short* __restrict__ wf,
    const int* __restrict__ rows, int* __restrict__ chunk_hist,
    int* __restrict__ chunk_sb, int n_edges, int nb, int nsb) {
  __shared__ int h[NB_MAX];
  const int bid = blockIdx.x;
  const int t = threadIdx.x;

  if (bid < 2) {              // ---- wf_pack role (2048 entries) ----
    int tid = bid * 1024 + t;
    int ks = tid >> 9;
    int rem = tid & 511;
    int nt = rem >> 6;
    int lane = rem & 63;
    int n = nt * 16 + (lane & 15);
    int k0 = ks * 32 + (lane >> 4) * 8;
    unsigned short v[8];
#pragma unroll
    for (int j = 0; j < 8; ++j) v[j] = f2bf(W[(k0 + j) * D + n]);
    uint4 o;
    o.x = (unsigned)v[0] | ((unsigned)v[1] << 16);
    o.y = (unsigned)v[2] | ((unsigned)v[3] << 16);
    o.z = (unsigned)v[4] | ((unsigned)v[5] << 16);
    o.w = (unsigned)v[6] | ((unsigned)v[7] << 16);
    ((uint4*)wf)[tid] = o;
    return;
  }

  // ---- histogram role ----
  h[t] = 0;
  __syncthreads();
  int c = bid - 2;
  int lo = c * CHN;
  int hi = min(lo + CHN, n_edges);
  for (int i = lo + t; i < hi; i += 1024) atomicAdd(&h[rows[i] >> 7], 1);
  __syncthreads();
  for (int b = t; b < nb; b += 1024) chunk_hist[b * CSTRIDE + c] = h[b];
  if (t < nsb) {
    int s = 0;
#pragma unroll
    for (int k = 0; k < 16; ++k) s += h[(t << 4) + k];
    chunk_sb[t * CSTRIDE + c] = s;
  }
}

// ---------------------------------------------------------------------------
// K1 (P1): partition edges into nsb super-bucket regions (sb = row>>11).
// Proven R8 form: block-parallel contiguous strip sums over transposed
// chunk_sb -> deterministic bases; LDS cursor scatter; block 0 publishes
// sb_off. Runs ~84 edges = 672 B per (chunk,sb) -> clean lines.
// Payload: ((row&2047)<<17)|col , val.
// ---------------------------------------------------------------------------
__global__ __launch_bounds__(1024) void p1_kernel(
    const int* __restrict__ rows, const int* __restrict__ cols,
    const float* __restrict__ vals, const int* __restrict__ chunk_sb,
    int* __restrict__ sb_off, int2* __restrict__ tmp1,
    int n_edges, int nchunks, int nsb) {
  __shared__ int ptot[1024];
  __shared__ int ppre[1024];
  __shared__ int sbt[SBMAX];
  __shared__ int sbo[SBMAX + 1];
  __shared__ int base_s[SBMAX];
  __shared__ int h[SBMAX];
  const int c = blockIdx.x;
  const int t = threadIdx.x;

  {
    int s = t >> 4, g = t & 15;
    int tp = 0, pp = 0;
    if (s < nsb) {
      int strip = (nchunks + 15) >> 4;          // 25
      int a = g * strip;
      int b2 = min(a + strip, nchunks);
      const int* rowp = chunk_sb + s * CSTRIDE;
      for (int cc = a; cc < b2; ++cc) {
        int v = rowp[cc];
        tp += v;
        pp += (cc < c) ? v : 0;
      }
    }
    ptot[t] = tp;
    ppre[t] = pp;
  }
  __syncthreads();
  if (t < nsb) {
    int tp = 0, pp = 0;
#pragma unroll
    for (int g = 0; g < 16; ++g) { tp += ptot[(t << 4) + g]; pp += ppre[(t << 4) + g]; }
    sbt[t] = tp;
    base_s[t] = pp;
    h[t] = 0;
  }
  __syncthreads();
  if (t == 0) {
    int run = 0;
    for (int s = 0; s < nsb; ++s) { sbo[s] = run; run += sbt[s]; }
    sbo[nsb] = run;   // == n_edges
  }
  __syncthreads();
  if (t < nsb) base_s[t] += sbo[t];
  if (c == 0 && t <= nsb) sb_off[t] = sbo[t];
  __syncthreads();

  int lo = c * CHN;
  int hi = min(lo + CHN, n_edges);
  for (int i = lo + t; i < hi; i += 1024) {
    int r = rows[i];
    int s = r >> 11;
    int l = atomicAdd(&h[s], 1);
    tmp1[base_s[s] + l] =
        make_int2(((r & 2047) << 17) | cols[i], __float_as_int(vals[i]));
  }
}

// ---------------------------------------------------------------------------
// K2 (P2): split super-buckets into final 128-row buckets, fully
// deterministic (no cursors, no scan dispatch). Block (s,j) covers chunk
// range [c0,c1); per its 16 buckets, 64 lanes strip-sum the CONTIGUOUS
// transposed chunk_hist row -> {tot, pre(<c0), mid([c0,c1))}. From these:
// local bucket offsets (loff), exact read range [a,bend), exact write bases
// (wbase). j==0 publishes bucket_off. Scatter runs ~128 edges = 1 KB.
// Output payload masks to 7 row bits: (p.x & 0x00FFFFFF).
// ---------------------------------------------------------------------------
__global__ __launch_bounds__(1024) void p2_kernel(
    const int* __restrict__ chunk_hist, const int* __restrict__ sb_off,
    int* __restrict__ bucket_off, const int2* __restrict__ tmp1,
    int2* __restrict__ tmp2, int nchunks, int nb, int nsb, int n_edges) {
  __shared__ int ptot[1024];
  __shared__ int ppre[1024];
  __shared__ int pmid[1024];
  __shared__ int loff[17];
  __shared__ int wbase[16];
  __shared__ int hh[16];
  __shared__ int aab[2];
  const int s = blockIdx.x >> 4;
  const int j = blockIdx.x & 15;
  const int t = threadIdx.x;
  const int c0 = (nchunks * j) >> 4;
  const int c1 = (nchunks * (j + 1)) >> 4;
  const int bb = t >> 6, k = t & 63;
  const int b = (s << 4) + bb;

  int tp = 0, pp = 0, mp = 0;
  if (b < nb) {
    int strip = (nchunks + 63) >> 6;          // 7
    int a0 = k * strip;
    int a1 = min(a0 + strip, nchunks);
    const int* rowp = chunk_hist + (size_t)b * CSTRIDE;
    for (int cc = a0; cc < a1; ++cc) {
      int v = rowp[cc];
      tp += v;
      if (cc < c0) pp += v;
      else if (cc < c1) mp += v;
    }
  }
  ptot[t] = tp; ppre[t] = pp; pmid[t] = mp;
  __syncthreads();
#pragma unroll
  for (int d = 32; d > 0; d >>= 1) {
    if (k < d) {
      ptot[t] += ptot[t + d];
      ppre[t] += ppre[t + d];
      pmid[t] += pmid[t + d];
    }
    __syncthreads();
  }
  if (t == 0) {
    int run = 0, presum = 0, midsum = 0;
    for (int q = 0; q < 16; ++q) {
      loff[q] = run;
      run += ptot[q << 6];
      presum += ppre[q << 6];
      midsum += pmid[q << 6];
    }
    loff[16] = run;
    aab[0] = sb_off[s] + presum;
    aab[1] = sb_off[s] + presum + midsum;
  }
  __syncthreads();
  if (t < 16) {
    wbase[t] = sb_off[s] + loff[t] + ppre[t << 6];
    hh[t] = 0;
    int bprime = (s << 4) + t;
    if (j == 0 && bprime < nb) bucket_off[bprime] = sb_off[s] + loff[t];
  }
  if (j == 0 && s == 0 && t == 0) bucket_off[nb] = n_edges;
  __syncthreads();

  const int a = aab[0], bend = aab[1];
  for (int i = a + t; i < bend; i += 1024) {
    int2 p = tmp1[i];
    int bi = (((unsigned)p.x) >> 24) & 15;
    int l = atomicAdd(&hh[bi], 1);
    tmp2[wbase[bi] + l] = make_int2(p.x & 0x00FFFFFF, p.y);
  }
}

// ---------------------------------------------------------------------------
// K3: x -> bf16 cast, lane-contiguous. Runs AFTER P2 (xh's top half overlays
// the then-dead tmp1).
// ---------------------------------------------------------------------------
__global__ __launch_bounds__(1024) void xcast_kernel(
    const float* __restrict__ x, unsigned int* __restrict__ xh2, int total4) {
  const float4* x4 = (const float4*)x;
  int base = blockIdx.x * 4096;
#pragma unroll
  for (int k = 0; k < 4; ++k) {
    int i = base + k * 1024 + threadIdx.x;
    if (i < total4) {
      float4 v = x4[i];
      unsigned lo = (unsigned)f2bf(v.x) | ((unsigned)f2bf(v.y) << 16);
      unsigned hi = (unsigned)f2bf(v.z) | ((unsigned)f2bf(v.w) << 16);
      ((uint2*)xh2)[i] = make_uint2(lo, hi);
    }
  }
}

// ---------------------------------------------------------------------------
// K4: fused in-LDS sort + register gather of y=adj@x + in-block MFMA GEMM.
// R5-verbatim (measured 75.6 us). out = (adj@x)@W + rowsum⊗b. One 1024-thr
// block (16 waves) per 128-row bucket; LDS overlay 69.6 KB -> 2 blocks/CU.
// ---------------------------------------------------------------------------
__global__ __launch_bounds__(1024, 8) void gather_gemm_kernel(
    const uint2* __restrict__ xh, const unsigned short* __restrict__ wf,
    const float* __restrict__ bias, const int* __restrict__ bucket_off,
    const int2* __restrict__ tmp, float* __restrict__ out, int n_nodes) {
  __shared__ __align__(16) char U[67584];
  __shared__ int cnt[128];
  __shared__ int scn[128];
  __shared__ int rs[129];
  __shared__ float rowsum[128];
  unsigned short* ys = (unsigned short*)U;             // [0,34816)
  int2* ebuf = (int2*)U;                               // [0,20480)
  int2* sbuf = (int2*)(U + 34816);                     // [34816,55296)
  unsigned short* wfs = (unsigned short*)(U + 34816);  // [34816,67584)
  const int t = threadIdx.x;
  const int b = blockIdx.x;

  // prefetch W fragments to registers (issue early, write late)
  const uint4* wf4 = (const uint4*)wf;
  uint4 wfr0 = wf4[t];
  uint4 wfr1 = wf4[t + 1024];

  const int lo = bucket_off[b];
  const int ne = bucket_off[b + 1] - lo;
  const int slot = t >> 5;       // 0..31
  const int lane = t & 31;

  if (ne <= CAP) {
    if (t < 128) cnt[t] = 0;
    __syncthreads();
    for (int i = t; i < ne; i += 1024) {
      int2 p = tmp[lo + i];
      ebuf[i] = p;
      atomicAdd(&cnt[((unsigned)p.x) >> 17], 1);
    }
    __syncthreads();
    if (t < 128) scn[t] = cnt[t];
    __syncthreads();
#pragma unroll
    for (int d = 1; d < 128; d <<= 1) {
      int v = (t < 128 && t >= d) ? scn[t - d] : 0;
      __syncthreads();
      if (t < 128) scn[t] += v;
      __syncthreads();
    }
    if (t < 128) {
      rs[t] = (t == 0) ? 0 : scn[t - 1];
      cnt[t] = 0;                // reuse as per-row cursor
    }
    __syncthreads();
    if (t == 0) rs[128] = scn[127];   // read only after next barrier
    for (int i = t; i < ne; i += 1024) {
      int2 p = ebuf[i];
      int r = ((unsigned)p.x) >> 17;
      int l = atomicAdd(&cnt[r], 1);
      sbuf[rs[r] + l] = p;
    }
    __syncthreads();
    // gather: slot handles rows slot, slot+32, ... ; y + rowsum per row
#pragma unroll
    for (int rr = 0; rr < 4; ++rr) {
      int row = slot + (rr << 5);
      int s = rs[row], e = rs[row + 1];
      float4 acc = make_float4(0.f, 0.f, 0.f, 0.f);
      float rsum = 0.f;
      int i = s;
      for (; i + 4 <= e; i += 4) {
        int2 p0 = sbuf[i + 0];
        int2 p1 = sbuf[i + 1];
        int2 p2 = sbuf[i + 2];
        int2 p3 = sbuf[i + 3];
        uint2 s0 = xh[((size_t)(p0.x & 0x1FFFF) << 5) + lane];
        uint2 s1 = xh[((size_t)(p1.x & 0x1FFFF) << 5) + lane];
        uint2 s2 = xh[((size_t)(p2.x & 0x1FFFF) << 5) + lane];
        uint2 s3 = xh[((size_t)(p3.x & 0x1FFFF) << 5) + lane];
        float v0 = __int_as_float(p0.y), v1 = __int_as_float(p1.y);
        float v2 = __int_as_float(p2.y), v3 = __int_as_float(p3.y);
        rsum += v0 + v1 + v2 + v3;
        acc.x += v0 * __uint_as_float(s0.x << 16);
        acc.y += v0 * __uint_as_float(s0.x & 0xffff0000u);
        acc.z += v0 * __uint_as_float(s0.y << 16);
        acc.w += v0 * __uint_as_float(s0.y & 0xffff0000u);
        acc.x += v1 * __uint_as_float(s1.x << 16);
        acc.y += v1 * __uint_as_float(s1.x & 0xffff0000u);
        acc.z += v1 * __uint_as_float(s1.y << 16);
        acc.w += v1 * __uint_as_float(s1.y & 0xffff0000u);
        acc.x += v2 * __uint_as_float(s2.x << 16);
        acc.y += v2 * __uint_as_float(s2.x & 0xffff0000u);
        acc.z += v2 * __uint_as_float(s2.y << 16);
        acc.w += v2 * __uint_as_float(s2.y & 0xffff0000u);
        acc.x += v3 * __uint_as_float(s3.x << 16);
        acc.y += v3 * __uint_as_float(s3.x & 0xffff0000u);
        acc.z += v3 * __uint_as_float(s3.y << 16);
        acc.w += v3 * __uint_as_float(s3.y & 0xffff0000u);
      }
      for (; i < e; ++i) {
        int2 p = sbuf[i];
        float v = __int_as_float(p.y);
        uint2 sv = xh[((size_t)(p.x & 0x1FFFF) << 5) + lane];
        rsum += v;
        acc.x += v * __uint_as_float(sv.x << 16);
        acc.y += v * __uint_as_float(sv.x & 0xffff0000u);
        acc.z += v * __uint_as_float(sv.y << 16);
        acc.w += v * __uint_as_float(sv.y & 0xffff0000u);
      }
      unsigned u0 = (unsigned)f2bf(acc.x) | ((unsigned)f2bf(acc.y) << 16);
      unsigned u1 = (unsigned)f2bf(acc.z) | ((unsigned)f2bf(acc.w) << 16);
      *((uint2*)(ys + row * SP + lane * 4)) = make_uint2(u0, u1);
      if (lane == 0) rowsum[row] = rsum;
    }
  } else {
    // fallback (ne > CAP, ~ +11 sigma): filtered scan (exact)
#pragma unroll
    for (int rr = 0; rr < 4; ++rr) {
      int row = slot + (rr << 5);
      float4 acc = make_float4(0.f, 0.f, 0.f, 0.f);
      float rsum = 0.f;
      for (int i = 0; i < ne; ++i) {
        int2 p = tmp[lo + i];
        if ((int)(((unsigned)p.x) >> 17) != row) continue;
        float v = __int_as_float(p.y);
        uint2 sv = xh[((size_t)(p.x & 0x1FFFF) << 5) + lane];
        rsum += v;
        acc.x += v * __uint_as_float(sv.x << 16);
        acc.y += v * __uint_as_float(sv.x & 0xffff0000u);
        acc.z += v * __uint_as_float(sv.y << 16);
        acc.w += v * __uint_as_float(sv.y & 0xffff0000u);
      }
      unsigned u0 = (unsigned)f2bf(acc.x) | ((unsigned)f2bf(acc.y) << 16);
      unsigned u1 = (unsigned)f2bf(acc.z) | ((unsigned)f2bf(acc.w) << 16);
      *((uint2*)(ys + row * SP + lane * 4)) = make_uint2(u0, u1);
      if (lane == 0) rowsum[row] = rsum;
    }
  }
  __syncthreads();

  // drop prefetched W fragments into LDS (over dead sbuf)
  uint4* wfs4 = (uint4*)wfs;
  wfs4[t] = wfr0;
  wfs4[t + 1024] = wfr1;
  __syncthreads();

  // in-block GEMM: 16 waves, each 32x32 of the 128x128 tile
  const int l64 = t & 63;
  const int w = t >> 6;
  const int m = l64 & 15, q = l64 >> 4;
  const int rb = (w & 3) * 32;
  const int cb = (w >> 2) * 32;

  floatx4 acc2[2][2];
#pragma unroll
  for (int rt = 0; rt < 2; ++rt)
#pragma unroll
    for (int ct = 0; ct < 2; ++ct) {
      acc2[rt][ct][0] = 0.f; acc2[rt][ct][1] = 0.f;
      acc2[rt][ct][2] = 0.f; acc2[rt][ct][3] = 0.f;
    }

#pragma unroll
  for (int ks = 0; ks < 4; ++ks) {
    short8 af[2], bfr[2];
#pragma unroll
    for (int rt = 0; rt < 2; ++rt)
      af[rt] = *((const short8*)(ys + (rb + rt * 16 + m) * SP + ks * 32 + q * 8));
#pragma unroll
    for (int ct = 0; ct < 2; ++ct) {
      int nt = (cb >> 4) + ct;
      bfr[ct] = *((const short8*)(wfs + ((ks * 8 + nt) * 64 + l64) * 8));
    }
#pragma unroll
    for (int rt = 0; rt < 2; ++rt)
#pragma unroll
      for (int ct = 0; ct < 2; ++ct)
        acc2[rt][ct] = __builtin_amdgcn_mfma_f32_16x16x32_bf16(
            af[rt], bfr[ct], acc2[rt][ct], 0, 0, 0);
  }

  // epilogue: out = acc + rowsum[row]*b[col]; C/D map row=(lane>>4)*4+r, col=m
  float b0 = bias[cb + m];
  float b1 = bias[cb + 16 + m];
#pragma unroll
  for (int rt = 0; rt < 2; ++rt)
#pragma unroll
    for (int ct = 0; ct < 2; ++ct) {
      float bc = ct ? b1 : b0;
#pragma unroll
      for (int r = 0; r < 4; ++r) {
        int row = rb + rt * 16 + q * 4 + r;
        int col = cb + ct * 16 + m;
        int node = (b << 7) + row;
        if (node < n_nodes)
          out[(size_t)node * D + col] = acc2[rt][ct][r] + rowsum[row] * bc;
      }
    }
}

extern "C" void kernel_launch(void* const* d_in, const int* in_sizes, int n_in,
                              void* d_out, int out_size, void* d_ws, size_t ws_size,
                              hipStream_t stream) {
  const float* x    = (const float*)d_in[0];
  const int*   rows = (const int*)d_in[1];
  const int*   cols = (const int*)d_in[2];
  const float* vals = (const float*)d_in[3];
  const float* W    = (const float*)d_in[4];
  const float* b    = (const float*)d_in[5];
  float* out = (float*)d_out;

  int n_nodes = in_sizes[0] / D;
  int n_edges = in_sizes[1];
  int nb = (n_nodes + 127) >> 7;              // 782 final buckets
  int nsb = (nb + 15) >> 4;                   // 49 super-buckets
  int nchunks = (n_edges + CHN - 1) / CHN;    // 391 chunks
  int total4 = (n_nodes * D) >> 2;

  // Workspace overlay (38.44 MB, proven budget):
  //   [0, 12.8M)      tmp2 (final-bucket edges)
  //   [12.8M, 38.4M)  xh (bf16 x) -- written by xcast AFTER p2
  //   [25.6M, 38.4M)  tmp1 (sb-partitioned edges) -- dead after p2;
  //                   xh's top half overlays it
  //   [38.4M, ...)    sb_off + bucket_off + wf
  // chunk_hist (782x512 ints = 1.6 MB) + chunk_sb (49x512) live in `out`
  // as scratch (written K0, read K1/K2, dead before K4 writes out).
  char* ws = (char*)d_ws;
  int2* tmp2         = (int2*)(ws);
  unsigned short* xh = (unsigned short*)(ws + 12800000);
  int2* tmp1         = (int2*)(ws + 25600000);
  char* mb           = ws + 38400000;
  int* sb_off        = (int*)(mb);                      //    512 B
  int* bucket_off    = (int*)(mb + 512);                //  4,096 B (nb+1)
  unsigned short* wf = (unsigned short*)(mb + 4608);    // 32,768 B
  int* chunk_hist    = (int*)out;                       // 1,601,536 B
  int* chunk_sb      = (int*)((char*)out + 1605632);    //   100,352 B

  prep_kernel<<<dim3(2 + nchunks), dim3(1024), 0, stream>>>(
      W, wf, rows, chunk_hist, chunk_sb, n_edges, nb, nsb);

  p1_kernel<<<dim3(nchunks), dim3(1024), 0, stream>>>(
      rows, cols, vals, chunk_sb, sb_off, tmp1, n_edges, nchunks, nsb);

  p2_kernel<<<dim3(nsb * 16), dim3(1024), 0, stream>>>(
      chunk_hist, sb_off, bucket_off, tmp1, tmp2, nchunks, nb, nsb, n_edges);

  xcast_kernel<<<dim3((total4 + 4095) / 4096), dim3(1024), 0, stream>>>(
      x, (unsigned int*)xh, total4);

  gather_gemm_kernel<<<dim3(nb), dim3(1024), 0, stream>>>(
      (const uint2*)xh, wf, b, bucket_off, tmp2, out, n_nodes);
}